// Round 18
// baseline (271.480 us; speedup 1.0000x reference)
//
#include <hip/hip_runtime.h>
#include <math.h>

typedef float fx4    __attribute__((ext_vector_type(4)));
typedef float f32x16 __attribute__((ext_vector_type(16)));
typedef short bf16x8 __attribute__((ext_vector_type(8)));
typedef unsigned int ux4 __attribute__((ext_vector_type(4)));

#define TM    64
#define DDIM  2048
#define ENUM  64

__device__ __forceinline__ unsigned short bf16_rne(float f) {
    unsigned int u = __builtin_bit_cast(unsigned int, f);
    unsigned int r = u + 0x7FFFu + ((u >> 16) & 1u);
    return (unsigned short)(r >> 16);
}
__device__ __forceinline__ float bf16_f32(unsigned short h) {
    unsigned int u = ((unsigned int)h) << 16;
    return __builtin_bit_cast(float, u);
}

// ---------------- kernel 1: W -> bf16x2 (H,M), frag-slot order (R15-proven) ----------------
// wsB 16-B slots: [split(2)][kt(128)][ct(4)][lane(64)]  -> 1.0 MB
__global__ __launch_bounds__(256)
void convert_w(const float* __restrict__ Wg, const float* __restrict__ Wn,
               unsigned short* __restrict__ wsB) {
    const int t  = blockIdx.x * 256 + threadIdx.x;   // 0..32767
    const int l  = t & 63;
    const int ct = (t >> 6) & 3;
    const int kt = t >> 8;                            // 0..127
    const int col = ct * 32 + (l & 31);
    const int k0  = kt * 16 + (l >> 5) * 8;
    const float* src = ((col < ENUM) ? (Wg + (size_t)col * DDIM)
                                     : (Wn + (size_t)(col - ENUM) * DDIM)) + k0;
    bf16x8 vh, vm;
    #pragma unroll
    for (int j = 0; j < 8; ++j) {
        float v = src[j];
        unsigned short h = bf16_rne(v);
        float r1 = v - bf16_f32(h);
        unsigned short m = bf16_rne(r1);
        vh[j] = (short)h; vm[j] = (short)m;
    }
    *(bf16x8*)(wsB + ((size_t)(0 * 32768 + t)) * 8) = vh;
    *(bf16x8*)(wsB + ((size_t)(1 * 32768 + t)) * 8) = vm;
}

// in-register bf16x2 split via v_cvt_pk_bf16_f32 (RNE pack, 2 f32 -> 1 dword)
__device__ __forceinline__ void split2x8_cvt(fx4 a, fx4 b, bf16x8& H, bf16x8& M) {
    const float e0[4] = {a[0], a[2], b[0], b[2]};
    const float e1[4] = {a[1], a[3], b[1], b[3]};
    ux4 hw, mw;
    #pragma unroll
    for (int j = 0; j < 4; ++j) {
        float v0 = e0[j], v1 = e1[j];
        unsigned h;
        asm("v_cvt_pk_bf16_f32 %0, %1, %2" : "=v"(h) : "v"(v0), "v"(v1));
        float h0 = __builtin_bit_cast(float, h << 16);
        float h1 = __builtin_bit_cast(float, h & 0xFFFF0000u);
        float r0 = v0 - h0, r1 = v1 - h1;
        unsigned m;
        asm("v_cvt_pk_bf16_f32 %0, %1, %2" : "=v"(m) : "v"(r0), "v"(r1));
        hw[j] = h; mw[j] = m;
    }
    H = __builtin_bit_cast(bf16x8, hw);
    M = __builtin_bit_cast(bf16x8, mw);
}

#define MFMA32 __builtin_amdgcn_mfma_f32_32x32x16_bf16

// ---------------- kernel 2: 1 block/CU, 16 waves = rt(2) x kh(8), 4 waves/SIMD ----------------
// launch_bounds(1024, 1): arg2 = min BLOCKS/CU in this toolchain (R11-R17 evidence);
// 1 block x 16 waves = 4 waves/SIMD -> 128-VGPR cap, fits the 84-reg working set.
__global__ __launch_bounds__(1024, 1)
void noisy_topk_mfma(const float* __restrict__ x,
                     const float* __restrict__ eps,
                     const float* __restrict__ gb,
                     const float* __restrict__ nb,
                     const unsigned short* __restrict__ wsB,
                     float* __restrict__ out)
{
    __shared__ float hbuf[TM][132];     // 33.8 KB
    __shared__ float pv1[TM][16], pv2[TM][16];
    __shared__ int   pi1[TM][16], pi2[TM][16];
    __shared__ float tp1[TM], tp2[TM];
    __shared__ int   ti1[TM], ti2[TM];

    const int tid  = threadIdx.x;
    const int lane = tid & 63;
    const int wv   = tid >> 6;           // 0..15
    const int rt   = wv & 1;             // row-tile (32 rows)
    const int kh   = wv >> 1;            // K-eighth 0..7 (256 k = 16 ktiles)
    const int bs   = (blockIdx.x & 7) * 32 + (blockIdx.x >> 3);  // XCD swizzle (256 = 8*32)
    const int row0 = bs * TM;

    const int r32 = lane & 31;
    const int k8  = (lane >> 5) * 8;

    // A: direct global, MFMA fragment order (lane -> row rt*32 + r32, k offset k8)
    const float* xa = x + (size_t)(row0 + rt * 32 + r32) * DDIM + kh * 256 + k8;

    // B: wsB frag slots; elem off = ((s*128 + kh*16 + kt)*4 + ct)*512 + lane*8
    const unsigned short* bq = wsB + ((size_t)(kh * 16) * 4) * 512 + lane * 8;
    // per kt: +2048 ; per split s: +262144 ; per ct: +512

    f32x16 ac0 = {}, ac1 = {}, ac2 = {}, ac3 = {};

    // ---- 2-deep static pipeline buffers (R15-proven) ----
    fx4 A0_0, A0_1, A1_0, A1_1;
    bf16x8 B0[8], B1[8];                 // [ct*2+0]=H_ct, [ct*2+1]=M_ct

    #define LDA(n, kt) do { \
        n##_0 = *(const fx4*)(xa + (kt) * 16); \
        n##_1 = *(const fx4*)(xa + (kt) * 16 + 4); \
    } while (0)

    #define LDB(B, kt) do { \
        const unsigned short* _p = bq + (size_t)(kt) * 2048; \
        B[0] = *(const bf16x8*)(_p);                  \
        B[1] = *(const bf16x8*)(_p + 262144);         \
        B[2] = *(const bf16x8*)(_p + 512);            \
        B[3] = *(const bf16x8*)(_p + 512 + 262144);   \
        B[4] = *(const bf16x8*)(_p + 1024);           \
        B[5] = *(const bf16x8*)(_p + 1024 + 262144);  \
        B[6] = *(const bf16x8*)(_p + 1536);           \
        B[7] = *(const bf16x8*)(_p + 1536 + 262144);  \
    } while (0)

    // 16 MFMA (4 products x 4 col-tiles), same-acc distance 4
    #define KTILE(n, B) do { \
        bf16x8 Ah, Am; \
        split2x8_cvt(n##_0, n##_1, Ah, Am); \
        __builtin_amdgcn_s_setprio(1); \
        ac0 = MFMA32(Ah, B[0], ac0, 0, 0, 0); ac1 = MFMA32(Ah, B[2], ac1, 0, 0, 0); \
        ac2 = MFMA32(Ah, B[4], ac2, 0, 0, 0); ac3 = MFMA32(Ah, B[6], ac3, 0, 0, 0); \
        ac0 = MFMA32(Ah, B[1], ac0, 0, 0, 0); ac1 = MFMA32(Ah, B[3], ac1, 0, 0, 0); \
        ac2 = MFMA32(Ah, B[5], ac2, 0, 0, 0); ac3 = MFMA32(Ah, B[7], ac3, 0, 0, 0); \
        ac0 = MFMA32(Am, B[0], ac0, 0, 0, 0); ac1 = MFMA32(Am, B[2], ac1, 0, 0, 0); \
        ac2 = MFMA32(Am, B[4], ac2, 0, 0, 0); ac3 = MFMA32(Am, B[6], ac3, 0, 0, 0); \
        ac0 = MFMA32(Am, B[1], ac0, 0, 0, 0); ac1 = MFMA32(Am, B[3], ac1, 0, 0, 0); \
        ac2 = MFMA32(Am, B[5], ac2, 0, 0, 0); ac3 = MFMA32(Am, B[7], ac3, 0, 0, 0); \
        __builtin_amdgcn_s_setprio(0); \
    } while (0)

    // ---- prologue: fill 2-deep ----
    LDA(A0, 0); LDB(B0, 0);
    LDA(A1, 1); LDB(B1, 1);

    // ---- barrier-free K loop: 8 bodies x 2 ktiles (16 total per wave) ----
    for (int kt = 0; kt < 16; kt += 2) {
        const bool more = (kt + 2 < 16);
        KTILE(A0, B0);
        if (more) { LDA(A0, kt + 2); LDB(B0, kt + 2); }
        KTILE(A1, B1);
        if (more) { LDA(A1, kt + 3); LDB(B1, kt + 3); }
    }

    #undef KTILE
    #undef LDB
    #undef LDA

    // ---- combine 8 K-eighths in hbuf (C layout: col=lane&31, row=(r&3)+8*(r>>2)+4*(lane>>5)) ----
    const int rowb = rt * 32 + 4 * (lane >> 5);
    if (kh == 0) {
        #pragma unroll
        for (int r = 0; r < 16; ++r) {
            const int row = (r & 3) + 8 * (r >> 2) + rowb;
            hbuf[row][r32]      = ac0[r];
            hbuf[row][r32 + 32] = ac1[r];
            hbuf[row][r32 + 64] = ac2[r];
            hbuf[row][r32 + 96] = ac3[r];
        }
    }
    __syncthreads();
    #pragma unroll
    for (int ph = 1; ph < 8; ++ph) {
        if (kh == ph) {
            #pragma unroll
            for (int r = 0; r < 16; ++r) {
                const int row = (r & 3) + 8 * (r >> 2) + rowb;
                hbuf[row][r32]      += ac0[r];
                hbuf[row][r32 + 32] += ac1[r];
                hbuf[row][r32 + 64] += ac2[r];
                hbuf[row][r32 + 96] += ac3[r];
            }
        }
        __syncthreads();
    }

    // ---- epilogue: h = gate + eps*softplus(noise); partial top-2 (16 threads/row) ----
    const int rloc = tid >> 4;   // 0..63
    const int q    = tid & 15;   // experts q*4 .. q*4+3
    {
        float v1 = -INFINITY, v2 = -INFINITY;
        int   i1 = -1, i2 = -1;
        const float* ep = eps + (size_t)(row0 + rloc) * ENUM + q * 4;
        fx4 gv  = *(const fx4*)&hbuf[rloc][q * 4];
        fx4 nv  = *(const fx4*)&hbuf[rloc][ENUM + q * 4];
        fx4 ev  = *(const fx4*)(ep);
        fx4 gbv = *(const fx4*)(gb + q * 4);
        fx4 nbv = *(const fx4*)(nb + q * 4);
        #pragma unroll
        for (int j = 0; j < 4; ++j) {
            float nz = nv[j] + nbv[j];
            float sp = fmaxf(nz, 0.f) + log1pf(expf(-fabsf(nz)));
            float h  = gv[j] + gbv[j] + ev[j] * sp;
            int   e  = q * 4 + j;
            if (h > v1)      { v2 = v1; i2 = i1; v1 = h; i1 = e; }
            else if (h > v2) { v2 = h;  i2 = e; }
        }
        pv1[rloc][q] = v1; pv2[rloc][q] = v2;
        pi1[rloc][q] = i1; pi2[rloc][q] = i2;
    }
    __syncthreads();

    if (tid < TM) {
        float v1 = -INFINITY, v2 = -INFINITY;
        int   i1 = -1, i2 = -1;
        #pragma unroll
        for (int qq = 0; qq < 16; ++qq) {
            float a1 = pv1[tid][qq]; int b1 = pi1[tid][qq];
            float a2 = pv2[tid][qq]; int b2 = pi2[tid][qq];
            if (a1 > v1)      { v2 = v1; i2 = i1; v1 = a1; i1 = b1; }
            else if (a1 > v2) { v2 = a1; i2 = b1; }
            if (a2 > v1)      { v2 = v1; i2 = i1; v1 = a2; i1 = b2; }
            else if (a2 > v2) { v2 = a2; i2 = b2; }
        }
        float e2  = expf(v2 - v1);
        float inv = 1.f / (1.f + e2);
        tp1[tid] = inv;
        tp2[tid] = e2 * inv;
        ti1[tid] = i1; ti2[tid] = i2;
    }
    __syncthreads();

    {
        const int   orow = tid >> 4;
        const int   oq   = tid & 15;
        const int   a1 = ti1[orow], a2 = ti2[orow];
        const float p1 = tp1[orow], p2 = tp2[orow];
        float* op = out + (size_t)(row0 + orow) * ENUM + oq * 4;
        fx4 o;
        #pragma unroll
        for (int j = 0; j < 4; ++j) {
            int e = oq * 4 + j;
            o[j] = (e == a1) ? p1 : ((e == a2) ? p2 : 0.f);
        }
        *(fx4*)(op) = o;
    }
}

extern "C" void kernel_launch(void* const* d_in, const int* in_sizes, int n_in,
                              void* d_out, int out_size, void* d_ws, size_t ws_size,
                              hipStream_t stream) {
    const float* x   = (const float*)d_in[0];
    const float* eps = (const float*)d_in[1];
    const float* Wg  = (const float*)d_in[2];
    const float* gbp = (const float*)d_in[3];
    const float* Wn  = (const float*)d_in[4];
    const float* nbp = (const float*)d_in[5];
    float* out = (float*)d_out;
    unsigned short* wsB = (unsigned short*)d_ws;   // needs 1.0 MB

    hipLaunchKernelGGL(convert_w, dim3(128), dim3(256), 0, stream, Wg, Wn, wsB);

    const int M = in_sizes[0] / DDIM;    // 16384
    hipLaunchKernelGGL(noisy_topk_mfma, dim3(M / TM), dim3(1024), 0, stream,
                       x, eps, gbp, nbp, wsB, out);
}

// Round 19
// 64.952 us; speedup vs baseline: 4.1797x; 4.1797x over previous
//
#include <hip/hip_runtime.h>
#include <math.h>

typedef float fx4    __attribute__((ext_vector_type(4)));
typedef float f32x16 __attribute__((ext_vector_type(16)));
typedef short bf16x8 __attribute__((ext_vector_type(8)));
typedef unsigned int ux4 __attribute__((ext_vector_type(4)));

#define TM    64
#define DDIM  2048
#define ENUM  64

__device__ __forceinline__ unsigned short bf16_rne(float f) {
    unsigned int u = __builtin_bit_cast(unsigned int, f);
    unsigned int r = u + 0x7FFFu + ((u >> 16) & 1u);
    return (unsigned short)(r >> 16);
}
__device__ __forceinline__ float bf16_f32(unsigned short h) {
    unsigned int u = ((unsigned int)h) << 16;
    return __builtin_bit_cast(float, u);
}

// ---------------- kernel 1: W -> bf16x2 (H,M), frag-slot order (R15-proven) ----------------
// wsB 16-B slots: [split(2)][kt(128)][ct(4)][lane(64)]  -> 1.0 MB
__global__ __launch_bounds__(256)
void convert_w(const float* __restrict__ Wg, const float* __restrict__ Wn,
               unsigned short* __restrict__ wsB) {
    const int t  = blockIdx.x * 256 + threadIdx.x;   // 0..32767
    const int l  = t & 63;
    const int ct = (t >> 6) & 3;
    const int kt = t >> 8;                            // 0..127
    const int col = ct * 32 + (l & 31);
    const int k0  = kt * 16 + (l >> 5) * 8;
    const float* src = ((col < ENUM) ? (Wg + (size_t)col * DDIM)
                                     : (Wn + (size_t)(col - ENUM) * DDIM)) + k0;
    bf16x8 vh, vm;
    #pragma unroll
    for (int j = 0; j < 8; ++j) {
        float v = src[j];
        unsigned short h = bf16_rne(v);
        float r1 = v - bf16_f32(h);
        unsigned short m = bf16_rne(r1);
        vh[j] = (short)h; vm[j] = (short)m;
    }
    *(bf16x8*)(wsB + ((size_t)(0 * 32768 + t)) * 8) = vh;
    *(bf16x8*)(wsB + ((size_t)(1 * 32768 + t)) * 8) = vm;
}

// in-register bf16x2 split via v_cvt_pk_bf16_f32 (RNE pack, 2 f32 -> 1 dword)
__device__ __forceinline__ void split2x8_cvt(fx4 a, fx4 b, bf16x8& H, bf16x8& M) {
    const float e0[4] = {a[0], a[2], b[0], b[2]};
    const float e1[4] = {a[1], a[3], b[1], b[3]};
    ux4 hw, mw;
    #pragma unroll
    for (int j = 0; j < 4; ++j) {
        float v0 = e0[j], v1 = e1[j];
        unsigned h;
        asm("v_cvt_pk_bf16_f32 %0, %1, %2" : "=v"(h) : "v"(v0), "v"(v1));
        float h0 = __builtin_bit_cast(float, h << 16);
        float h1 = __builtin_bit_cast(float, h & 0xFFFF0000u);
        float r0 = v0 - h0, r1 = v1 - h1;
        unsigned m;
        asm("v_cvt_pk_bf16_f32 %0, %1, %2" : "=v"(m) : "v"(r0), "v"(r1));
        hw[j] = h; mw[j] = m;
    }
    H = __builtin_bit_cast(bf16x8, hw);
    M = __builtin_bit_cast(bf16x8, mw);
}

#define MFMA32 __builtin_amdgcn_mfma_f32_32x32x16_bf16

// ---------------- kernel 2: 32-AGPR waves -> 2 blocks/CU resident ----------------
// 8 waves = rt(2) x ct2(2) x kh(2); wave = 32 rows x 64 cols x 1024 k (64 ktiles).
// Total regs/wave ~110 (32 acc + ~78 arch) -> 4 waves/SIMD fit in the 512-reg file.
__global__ __launch_bounds__(512, 2)
void noisy_topk_mfma(const float* __restrict__ x,
                     const float* __restrict__ eps,
                     const float* __restrict__ gb,
                     const float* __restrict__ nb,
                     const unsigned short* __restrict__ wsB,
                     float* __restrict__ out)
{
    __shared__ float hbuf[TM][132];     // 33.8 KB
    __shared__ float pv1[TM][8], pv2[TM][8];
    __shared__ int   pi1[TM][8], pi2[TM][8];
    __shared__ float tp1[TM], tp2[TM];
    __shared__ int   ti1[TM], ti2[TM];

    const int tid  = threadIdx.x;
    const int lane = tid & 63;
    const int wv   = tid >> 6;           // 0..7
    const int rt   = wv & 1;             // row-tile (32 rows)
    const int ct2  = (wv >> 1) & 1;      // col pair: cts {2*ct2, 2*ct2+1}
    const int kh   = wv >> 2;            // K-half 0..1 (1024 k = 64 ktiles)
    const int bs   = (blockIdx.x & 7) * 32 + (blockIdx.x >> 3);  // XCD swizzle (256 = 8*32)
    const int row0 = bs * TM;

    const int r32 = lane & 31;
    const int k8  = (lane >> 5) * 8;
    const int ctA = ct2 * 2;             // acc0 cols; acc1 = ctA+1

    // A: direct global, MFMA fragment order (lane -> row rt*32 + r32, k offset k8)
    const float* xa = x + (size_t)(row0 + rt * 32 + r32) * DDIM + kh * 1024 + k8;

    // B: wsB frag slots; elem off = ((s*128 + kh*64 + kt)*4 + ct)*512 + lane*8
    const unsigned short* bq = wsB + (((size_t)(kh * 64) * 4) + ctA) * 512 + lane * 8;
    // per kt: +2048 ; per split s: +262144 ; ctA+1: +512

    f32x16 ac0 = {}, ac1 = {};

    // ---- 2-deep static pipeline buffers ----
    fx4 A0_0, A0_1, A1_0, A1_1;
    bf16x8 B0[4], B1[4];   // [0]=H_ctA [1]=H_ctB [2]=M_ctA [3]=M_ctB

    #define LDA(n, kt) do { \
        n##_0 = *(const fx4*)(xa + (kt) * 16); \
        n##_1 = *(const fx4*)(xa + (kt) * 16 + 4); \
    } while (0)

    #define LDB(B, kt) do { \
        const unsigned short* _p = bq + (size_t)(kt) * 2048; \
        B[0] = *(const bf16x8*)(_p);                  \
        B[1] = *(const bf16x8*)(_p + 512);            \
        B[2] = *(const bf16x8*)(_p + 262144);         \
        B[3] = *(const bf16x8*)(_p + 512 + 262144);   \
    } while (0)

    // 8 MFMA (4 products x 2 col-tiles), ac0/ac1 alternate (same-acc distance 2)
    #define KTILE(n, B) do { \
        bf16x8 Ah, Am; \
        split2x8_cvt(n##_0, n##_1, Ah, Am); \
        __builtin_amdgcn_s_setprio(1); \
        ac0 = MFMA32(Ah, B[0], ac0, 0, 0, 0); ac1 = MFMA32(Ah, B[1], ac1, 0, 0, 0); \
        ac0 = MFMA32(Ah, B[2], ac0, 0, 0, 0); ac1 = MFMA32(Ah, B[3], ac1, 0, 0, 0); \
        ac0 = MFMA32(Am, B[0], ac0, 0, 0, 0); ac1 = MFMA32(Am, B[1], ac1, 0, 0, 0); \
        ac0 = MFMA32(Am, B[2], ac0, 0, 0, 0); ac1 = MFMA32(Am, B[3], ac1, 0, 0, 0); \
        __builtin_amdgcn_s_setprio(0); \
    } while (0)

    // ---- prologue: fill 2-deep ----
    LDA(A0, 0); LDB(B0, 0);
    LDA(A1, 1); LDB(B1, 1);

    // ---- barrier-free K loop: 32 bodies x 2 ktiles (64 total per wave) ----
    for (int kt = 0; kt < 64; kt += 2) {
        const bool more = (kt + 2 < 64);
        KTILE(A0, B0);
        if (more) { LDA(A0, kt + 2); LDB(B0, kt + 2); }
        KTILE(A1, B1);
        if (more) { LDA(A1, kt + 3); LDB(B1, kt + 3); }
    }

    #undef KTILE
    #undef LDB
    #undef LDA

    // ---- combine K-halves in hbuf (C layout: col=lane&31, row=(r&3)+8*(r>>2)+4*(lane>>5)) ----
    const int rowb = rt * 32 + 4 * (lane >> 5);
    const int colA = ctA * 32 + r32;
    if (kh == 0) {
        #pragma unroll
        for (int r = 0; r < 16; ++r) {
            const int row = (r & 3) + 8 * (r >> 2) + rowb;
            hbuf[row][colA]      = ac0[r];
            hbuf[row][colA + 32] = ac1[r];
        }
    }
    __syncthreads();
    if (kh == 1) {
        #pragma unroll
        for (int r = 0; r < 16; ++r) {
            const int row = (r & 3) + 8 * (r >> 2) + rowb;
            hbuf[row][colA]      += ac0[r];
            hbuf[row][colA + 32] += ac1[r];
        }
    }
    __syncthreads();

    // ---- epilogue (R15-proven): h = gate + eps*softplus(noise); top-2; softmax; store ----
    const int rloc = tid >> 3;   // 0..63
    const int q    = tid & 7;    // experts q*8 .. q*8+7
    {
        float v1 = -INFINITY, v2 = -INFINITY;
        int   i1 = -1, i2 = -1;
        const float* ep = eps + (size_t)(row0 + rloc) * ENUM + q * 8;
        #pragma unroll
        for (int v = 0; v < 2; ++v) {
            fx4 gv  = *(const fx4*)&hbuf[rloc][q * 8 + v * 4];
            fx4 nv  = *(const fx4*)&hbuf[rloc][ENUM + q * 8 + v * 4];
            fx4 ev  = *(const fx4*)(ep + v * 4);
            fx4 gbv = *(const fx4*)(gb + q * 8 + v * 4);
            fx4 nbv = *(const fx4*)(nb + q * 8 + v * 4);
            #pragma unroll
            for (int j = 0; j < 4; ++j) {
                float nz = nv[j] + nbv[j];
                float sp = fmaxf(nz, 0.f) + log1pf(expf(-fabsf(nz)));
                float h  = gv[j] + gbv[j] + ev[j] * sp;
                int   e  = q * 8 + v * 4 + j;
                if (h > v1)      { v2 = v1; i2 = i1; v1 = h; i1 = e; }
                else if (h > v2) { v2 = h;  i2 = e; }
            }
        }
        pv1[rloc][q] = v1; pv2[rloc][q] = v2;
        pi1[rloc][q] = i1; pi2[rloc][q] = i2;
    }
    __syncthreads();

    if (tid < TM) {
        float v1 = -INFINITY, v2 = -INFINITY;
        int   i1 = -1, i2 = -1;
        #pragma unroll
        for (int qq = 0; qq < 8; ++qq) {
            float a1 = pv1[tid][qq]; int b1 = pi1[tid][qq];
            float a2 = pv2[tid][qq]; int b2 = pi2[tid][qq];
            if (a1 > v1)      { v2 = v1; i2 = i1; v1 = a1; i1 = b1; }
            else if (a1 > v2) { v2 = a1; i2 = b1; }
            if (a2 > v1)      { v2 = v1; i2 = i1; v1 = a2; i1 = b2; }
            else if (a2 > v2) { v2 = a2; i2 = b2; }
        }
        float e2  = expf(v2 - v1);
        float inv = 1.f / (1.f + e2);
        tp1[tid] = inv;
        tp2[tid] = e2 * inv;
        ti1[tid] = i1; ti2[tid] = i2;
    }
    __syncthreads();

    {
        const int   orow = tid >> 3;
        const int   oq   = tid & 7;
        const int   a1 = ti1[orow], a2 = ti2[orow];
        const float p1 = tp1[orow], p2 = tp2[orow];
        float* op = out + (size_t)(row0 + orow) * ENUM + oq * 8;
        #pragma unroll
        for (int v = 0; v < 2; ++v) {
            fx4 o;
            #pragma unroll
            for (int j = 0; j < 4; ++j) {
                int e = oq * 8 + v * 4 + j;
                o[j] = (e == a1) ? p1 : ((e == a2) ? p2 : 0.f);
            }
            *(fx4*)(op + v * 4) = o;
        }
    }
}

extern "C" void kernel_launch(void* const* d_in, const int* in_sizes, int n_in,
                              void* d_out, int out_size, void* d_ws, size_t ws_size,
                              hipStream_t stream) {
    const float* x   = (const float*)d_in[0];
    const float* eps = (const float*)d_in[1];
    const float* Wg  = (const float*)d_in[2];
    const float* gbp = (const float*)d_in[3];
    const float* Wn  = (const float*)d_in[4];
    const float* nbp = (const float*)d_in[5];
    float* out = (float*)d_out;
    unsigned short* wsB = (unsigned short*)d_ws;   // needs 1.0 MB

    hipLaunchKernelGGL(convert_w, dim3(128), dim3(256), 0, stream, Wg, Wn, wsB);

    const int M = in_sizes[0] / DDIM;    // 16384
    hipLaunchKernelGGL(noisy_topk_mfma, dim3(M / TM), dim3(512), 0, stream,
                       x, eps, gbp, nbp, wsB, out);
}

// Round 21
// 56.331 us; speedup vs baseline: 4.8194x; 1.1530x over previous
//
#include <hip/hip_runtime.h>
#include <math.h>

typedef float fx4    __attribute__((ext_vector_type(4)));
typedef float f32x16 __attribute__((ext_vector_type(16)));
typedef short bf16x8 __attribute__((ext_vector_type(8)));
typedef unsigned int ux4 __attribute__((ext_vector_type(4)));

#define TM    64
#define DDIM  2048
#define ENUM  64

__device__ __forceinline__ unsigned short bf16_rne(float f) {
    unsigned int u = __builtin_bit_cast(unsigned int, f);
    unsigned int r = u + 0x7FFFu + ((u >> 16) & 1u);
    return (unsigned short)(r >> 16);
}
__device__ __forceinline__ float bf16_f32(unsigned short h) {
    unsigned int u = ((unsigned int)h) << 16;
    return __builtin_bit_cast(float, u);
}

// ---------------- kernel 1: W -> bf16x2 (H,M), frag-slot order (R15-proven) ----------------
// wsB 16-B slots: [split(2)][kt(128)][ct(4)][lane(64)]  -> 1.0 MB
__global__ __launch_bounds__(256)
void convert_w(const float* __restrict__ Wg, const float* __restrict__ Wn,
               unsigned short* __restrict__ wsB) {
    const int t  = blockIdx.x * 256 + threadIdx.x;   // 0..32767
    const int l  = t & 63;
    const int ct = (t >> 6) & 3;
    const int kt = t >> 8;                            // 0..127
    const int col = ct * 32 + (l & 31);
    const int k0  = kt * 16 + (l >> 5) * 8;
    const float* src = ((col < ENUM) ? (Wg + (size_t)col * DDIM)
                                     : (Wn + (size_t)(col - ENUM) * DDIM)) + k0;
    bf16x8 vh, vm;
    #pragma unroll
    for (int j = 0; j < 8; ++j) {
        float v = src[j];
        unsigned short h = bf16_rne(v);
        float r1 = v - bf16_f32(h);
        unsigned short m = bf16_rne(r1);
        vh[j] = (short)h; vm[j] = (short)m;
    }
    *(bf16x8*)(wsB + ((size_t)(0 * 32768 + t)) * 8) = vh;
    *(bf16x8*)(wsB + ((size_t)(1 * 32768 + t)) * 8) = vm;
}

// in-register bf16x2 split via v_cvt_pk_bf16_f32 (RNE pack, 2 f32 -> 1 dword)
__device__ __forceinline__ void split2x8_cvt(fx4 a, fx4 b, bf16x8& H, bf16x8& M) {
    const float e0[4] = {a[0], a[2], b[0], b[2]};
    const float e1[4] = {a[1], a[3], b[1], b[3]};
    ux4 hw, mw;
    #pragma unroll
    for (int j = 0; j < 4; ++j) {
        float v0 = e0[j], v1 = e1[j];
        unsigned h;
        asm("v_cvt_pk_bf16_f32 %0, %1, %2" : "=v"(h) : "v"(v0), "v"(v1));
        float h0 = __builtin_bit_cast(float, h << 16);
        float h1 = __builtin_bit_cast(float, h & 0xFFFF0000u);
        float r0 = v0 - h0, r1 = v1 - h1;
        unsigned m;
        asm("v_cvt_pk_bf16_f32 %0, %1, %2" : "=v"(m) : "v"(r0), "v"(r1));
        hw[j] = h; mw[j] = m;
    }
    H = __builtin_bit_cast(bf16x8, hw);
    M = __builtin_bit_cast(bf16x8, mw);
}

#define MFMA32 __builtin_amdgcn_mfma_f32_32x32x16_bf16

// ---------------- kernel 2: R15 structure + 4-deep A pipeline (trip count FIXED) ----------------
// 8 waves = rt(2) x kh(4); wave = 32 rows x 128 cols x 512 k = 32 ktiles, 16 MFMA/kt.
// A prefetch distance 4 ktiles (~2048 cyc >= ~900 cyc HBM/L3); B 2-deep (L2).
__global__ __launch_bounds__(512, 2)
void noisy_topk_mfma(const float* __restrict__ x,
                     const float* __restrict__ eps,
                     const float* __restrict__ gb,
                     const float* __restrict__ nb,
                     const unsigned short* __restrict__ wsB,
                     float* __restrict__ out)
{
    __shared__ float hbuf[TM][132];     // 33.8 KB
    __shared__ float pv1[TM][8], pv2[TM][8];
    __shared__ int   pi1[TM][8], pi2[TM][8];
    __shared__ float tp1[TM], tp2[TM];
    __shared__ int   ti1[TM], ti2[TM];

    const int tid  = threadIdx.x;
    const int lane = tid & 63;
    const int wv   = tid >> 6;           // 0..7
    const int rt   = wv & 1;             // row-tile (32 rows)
    const int kh   = wv >> 1;            // k quarter 0..3 (512 k = 32 ktiles)
    const int bs   = (blockIdx.x & 7) * 32 + (blockIdx.x >> 3);  // XCD swizzle (256 = 8*32)
    const int row0 = bs * TM;

    const int r32 = lane & 31;
    const int k8  = (lane >> 5) * 8;

    // A: direct global, MFMA fragment order (lane -> row rt*32 + r32, k offset k8)
    const float* xa = x + (size_t)(row0 + rt * 32 + r32) * DDIM + kh * 512 + k8;

    // B: wsB frag slots; elem off = ((s*128 + kh*32 + kt)*4 + ct)*512 + lane*8
    const unsigned short* bq = wsB + ((size_t)(kh * 32) * 4) * 512 + lane * 8;
    // per kt: +2048 ; per split s: +262144 ; per ct: +512

    f32x16 ac0 = {}, ac1 = {}, ac2 = {}, ac3 = {};

    // ---- pipeline buffers: A 4-deep, B 2-deep (all indices compile-time) ----
    fx4 A0_0, A0_1, A1_0, A1_1, A2_0, A2_1, A3_0, A3_1;
    bf16x8 B0[8], B1[8];                 // [ct*2+0]=H_ct, [ct*2+1]=M_ct

    #define LDA(n, kt) do { \
        n##_0 = *(const fx4*)(xa + (kt) * 16); \
        n##_1 = *(const fx4*)(xa + (kt) * 16 + 4); \
    } while (0)

    #define LDB(B, kt) do { \
        const unsigned short* _p = bq + (size_t)(kt) * 2048; \
        B[0] = *(const bf16x8*)(_p);                  \
        B[1] = *(const bf16x8*)(_p + 262144);         \
        B[2] = *(const bf16x8*)(_p + 512);            \
        B[3] = *(const bf16x8*)(_p + 512 + 262144);   \
        B[4] = *(const bf16x8*)(_p + 1024);           \
        B[5] = *(const bf16x8*)(_p + 1024 + 262144);  \
        B[6] = *(const bf16x8*)(_p + 1536);           \
        B[7] = *(const bf16x8*)(_p + 1536 + 262144);  \
    } while (0)

    // 16 MFMA (4 products x 4 col-tiles), same-acc distance 4
    #define KTILE(n, B) do { \
        bf16x8 Ah, Am; \
        split2x8_cvt(n##_0, n##_1, Ah, Am); \
        __builtin_amdgcn_s_setprio(1); \
        ac0 = MFMA32(Ah, B[0], ac0, 0, 0, 0); ac1 = MFMA32(Ah, B[2], ac1, 0, 0, 0); \
        ac2 = MFMA32(Ah, B[4], ac2, 0, 0, 0); ac3 = MFMA32(Ah, B[6], ac3, 0, 0, 0); \
        ac0 = MFMA32(Ah, B[1], ac0, 0, 0, 0); ac1 = MFMA32(Ah, B[3], ac1, 0, 0, 0); \
        ac2 = MFMA32(Ah, B[5], ac2, 0, 0, 0); ac3 = MFMA32(Ah, B[7], ac3, 0, 0, 0); \
        ac0 = MFMA32(Am, B[0], ac0, 0, 0, 0); ac1 = MFMA32(Am, B[2], ac1, 0, 0, 0); \
        ac2 = MFMA32(Am, B[4], ac2, 0, 0, 0); ac3 = MFMA32(Am, B[6], ac3, 0, 0, 0); \
        ac0 = MFMA32(Am, B[1], ac0, 0, 0, 0); ac1 = MFMA32(Am, B[3], ac1, 0, 0, 0); \
        ac2 = MFMA32(Am, B[5], ac2, 0, 0, 0); ac3 = MFMA32(Am, B[7], ac3, 0, 0, 0); \
        __builtin_amdgcn_s_setprio(0); \
    } while (0)

    // ---- prologue: A 4-deep, B 2-deep ----
    LDA(A0, 0); LDA(A1, 1); LDA(A2, 2); LDA(A3, 3);
    LDB(B0, 0); LDB(B1, 1);

    // ---- barrier-free K loop: 8 bodies x 4 ktiles (32 total per wave) ----
    for (int kt = 0; kt < 32; kt += 4) {
        KTILE(A0, B0);
        if (kt + 4 < 32) LDA(A0, kt + 4);
        if (kt + 2 < 32) LDB(B0, kt + 2);
        KTILE(A1, B1);
        if (kt + 5 < 32) LDA(A1, kt + 5);
        if (kt + 3 < 32) LDB(B1, kt + 3);
        KTILE(A2, B0);
        if (kt + 6 < 32) LDA(A2, kt + 6);
        if (kt + 4 < 32) LDB(B0, kt + 4);
        KTILE(A3, B1);
        if (kt + 7 < 32) LDA(A3, kt + 7);
        if (kt + 5 < 32) LDB(B1, kt + 5);
    }

    #undef KTILE
    #undef LDB
    #undef LDA

    // ---- combine K-quarters in hbuf (C layout: col=lane&31, row=(r&3)+8*(r>>2)+4*(lane>>5)) ----
    const int rowb = rt * 32 + 4 * (lane >> 5);
    if (kh == 0) {
        #pragma unroll
        for (int r = 0; r < 16; ++r) {
            const int row = (r & 3) + 8 * (r >> 2) + rowb;
            hbuf[row][r32]      = ac0[r];
            hbuf[row][r32 + 32] = ac1[r];
            hbuf[row][r32 + 64] = ac2[r];
            hbuf[row][r32 + 96] = ac3[r];
        }
    }
    __syncthreads();
    #pragma unroll
    for (int ph = 1; ph < 4; ++ph) {
        if (kh == ph) {
            #pragma unroll
            for (int r = 0; r < 16; ++r) {
                const int row = (r & 3) + 8 * (r >> 2) + rowb;
                hbuf[row][r32]      += ac0[r];
                hbuf[row][r32 + 32] += ac1[r];
                hbuf[row][r32 + 64] += ac2[r];
                hbuf[row][r32 + 96] += ac3[r];
            }
        }
        __syncthreads();
    }

    // ---- epilogue (R15-proven): h = gate + eps*softplus(noise); top-2; softmax; store ----
    const int rloc = tid >> 3;   // 0..63
    const int q    = tid & 7;    // experts q*8 .. q*8+7
    {
        float v1 = -INFINITY, v2 = -INFINITY;
        int   i1 = -1, i2 = -1;
        const float* ep = eps + (size_t)(row0 + rloc) * ENUM + q * 8;
        #pragma unroll
        for (int v = 0; v < 2; ++v) {
            fx4 gv  = *(const fx4*)&hbuf[rloc][q * 8 + v * 4];
            fx4 nv  = *(const fx4*)&hbuf[rloc][ENUM + q * 8 + v * 4];
            fx4 ev  = *(const fx4*)(ep + v * 4);
            fx4 gbv = *(const fx4*)(gb + q * 8 + v * 4);
            fx4 nbv = *(const fx4*)(nb + q * 8 + v * 4);
            #pragma unroll
            for (int j = 0; j < 4; ++j) {
                float nz = nv[j] + nbv[j];
                float sp = fmaxf(nz, 0.f) + log1pf(expf(-fabsf(nz)));
                float h  = gv[j] + gbv[j] + ev[j] * sp;
                int   e  = q * 8 + v * 4 + j;
                if (h > v1)      { v2 = v1; i2 = i1; v1 = h; i1 = e; }
                else if (h > v2) { v2 = h;  i2 = e; }
            }
        }
        pv1[rloc][q] = v1; pv2[rloc][q] = v2;
        pi1[rloc][q] = i1; pi2[rloc][q] = i2;
    }
    __syncthreads();

    if (tid < TM) {
        float v1 = -INFINITY, v2 = -INFINITY;
        int   i1 = -1, i2 = -1;
        #pragma unroll
        for (int qq = 0; qq < 8; ++qq) {
            float a1 = pv1[tid][qq]; int b1 = pi1[tid][qq];
            float a2 = pv2[tid][qq]; int b2 = pi2[tid][qq];
            if (a1 > v1)      { v2 = v1; i2 = i1; v1 = a1; i1 = b1; }
            else if (a1 > v2) { v2 = a1; i2 = b1; }
            if (a2 > v1)      { v2 = v1; i2 = i1; v1 = a2; i1 = b2; }
            else if (a2 > v2) { v2 = a2; i2 = b2; }
        }
        float e2  = expf(v2 - v1);
        float inv = 1.f / (1.f + e2);
        tp1[tid] = inv;
        tp2[tid] = e2 * inv;
        ti1[tid] = i1; ti2[tid] = i2;
    }
    __syncthreads();

    {
        const int   orow = tid >> 3;
        const int   oq   = tid & 7;
        const int   a1 = ti1[orow], a2 = ti2[orow];
        const float p1 = tp1[orow], p2 = tp2[orow];
        float* op = out + (size_t)(row0 + orow) * ENUM + oq * 8;
        #pragma unroll
        for (int v = 0; v < 2; ++v) {
            fx4 o;
            #pragma unroll
            for (int j = 0; j < 4; ++j) {
                int e = oq * 8 + v * 4 + j;
                o[j] = (e == a1) ? p1 : ((e == a2) ? p2 : 0.f);
            }
            *(fx4*)(op + v * 4) = o;
        }
    }
}

extern "C" void kernel_launch(void* const* d_in, const int* in_sizes, int n_in,
                              void* d_out, int out_size, void* d_ws, size_t ws_size,
                              hipStream_t stream) {
    const float* x   = (const float*)d_in[0];
    const float* eps = (const float*)d_in[1];
    const float* Wg  = (const float*)d_in[2];
    const float* gbp = (const float*)d_in[3];
    const float* Wn  = (const float*)d_in[4];
    const float* nbp = (const float*)d_in[5];
    float* out = (float*)d_out;
    unsigned short* wsB = (unsigned short*)d_ws;   // needs 1.0 MB

    hipLaunchKernelGGL(convert_w, dim3(128), dim3(256), 0, stream, Wg, Wn, wsB);

    const int M = in_sizes[0] / DDIM;    // 16384
    hipLaunchKernelGGL(noisy_topk_mfma, dim3(M / TM), dim3(512), 0, stream,
                       x, eps, gbp, nbp, wsB, out);
}